// Round 2
// baseline (8115.944 us; speedup 1.0000x reference)
//
#include <hip/hip_runtime.h>
#include <math.h>

// Problem constants: S=512, B=64, I=512, H=1024, fp32.
#define RS 512
#define RB 64
#define RI 512
#define RH 1024

#define NG   8    // groups (fast: physical XCDs; fallback: wgid&7)
#define WPG  32   // workgroups per group
#define BPG  8    // batches per group (64/8)

typedef float f32x4 __attribute__((ext_vector_type(4)));

// ---------------------------------------------------------------------------
// Kernel 1: Vx = x @ Vw^T + Vb   (unchanged — measured-correct)
// ---------------------------------------------------------------------------
__global__ __launch_bounds__(256) void vx_gemm(const float* __restrict__ A,
                                               const float* __restrict__ W,
                                               const float* __restrict__ bias,
                                               float* __restrict__ C,
                                               int M, int N, int K) {
    __shared__ __align__(16) float As[16][68];
    __shared__ __align__(16) float Bs[16][68];

    const int tx = threadIdx.x;
    const int ty = threadIdx.y;
    const int tid = ty * 16 + tx;
    const int m0 = blockIdx.y * 64;
    const int n0 = blockIdx.x * 64;

    float acc[4][4] = {};

    const int row  = tid >> 2;
    const int quad = tid & 3;

    for (int k0 = 0; k0 < K; k0 += 16) {
        float4 av = *(const float4*)&A[(size_t)(m0 + row) * K + k0 + quad * 4];
        float4 wv = *(const float4*)&W[(size_t)(n0 + row) * K + k0 + quad * 4];
        const int kq = quad * 4;
        As[kq + 0][row] = av.x; As[kq + 1][row] = av.y;
        As[kq + 2][row] = av.z; As[kq + 3][row] = av.w;
        Bs[kq + 0][row] = wv.x; Bs[kq + 1][row] = wv.y;
        Bs[kq + 2][row] = wv.z; Bs[kq + 3][row] = wv.w;
        __syncthreads();

        #pragma unroll
        for (int k = 0; k < 16; ++k) {
            float4 a = *(const float4*)&As[k][ty * 4];
            float4 b = *(const float4*)&Bs[k][tx * 4];
            float am[4] = {a.x, a.y, a.z, a.w};
            float bn[4] = {b.x, b.y, b.z, b.w};
            #pragma unroll
            for (int i = 0; i < 4; ++i)
                #pragma unroll
                for (int j = 0; j < 4; ++j)
                    acc[i][j] = fmaf(am[i], bn[j], acc[i][j]);
        }
        __syncthreads();
    }

    #pragma unroll
    for (int i = 0; i < 4; ++i) {
        const int m = m0 + ty * 4 + i;
        const int n = n0 + tx * 4;
        float4 o;
        o.x = acc[i][0] + bias[n + 0];
        o.y = acc[i][1] + bias[n + 1];
        o.z = acc[i][2] + bias[n + 2];
        o.w = acc[i][3] + bias[n + 3];
        *(float4*)&C[(size_t)m * N + n] = o;
    }
}

// ---------------------------------------------------------------------------
// Kernel 2: persistent recurrence.
//
// Census-verified XCD grouping with fallback:
//  - Every WG publishes s_getreg(HW_REG_XCC_ID)&7 to xcds[wgid] (agent scope)
//    and waits until all 256 entries are present (co-residency of all 256 WGs
//    is established by the round-0 kernel's working 256-WG spin barriers).
//  - If the census shows exactly 32 WGs per XCD id -> FAST path: group ==
//    physical XCD, slot == rank among same-XCD WGs. The h exchange then stays
//    inside one XCD's L2: producers use plain (CU-scope, write-through-L1)
//    stores; consumers use sc0 (SE-scope) loads served by the same L2.
//    This avoids the agent-scope (sc1) L2-bypass latency (~700-900 cy/hop).
//  - Otherwise -> FALLBACK: wgid-based grouping + agent-scope atomics
//    (the measured-correct round-0 protocol). Nothing can deadlock: fast
//    requires a verified bijective partition, fallback only co-residency.
// ---------------------------------------------------------------------------
__global__ __launch_bounds__(256, 1) void rnn_persistent(
    const float* __restrict__ Ww, const float* __restrict__ Wb,
    float* __restrict__ hseq, float* __restrict__ hfin,
    float* __restrict__ hex, int* __restrict__ flags, int* __restrict__ xcds)
{
    __shared__ __align__(16) float Hs[8256];      // [k][8b] + 4-float stagger/64k
    __shared__ __align__(16) float Red[16 * 272]; // v-major, stride 272
    __shared__ int sx[256];
    __shared__ int s_info;

    const int tid  = threadIdx.x;
    const int wgid = blockIdx.x;
    const int wave = tid >> 6, lane = tid & 63;

    // ---- census: publish my XCD id, wait for all, verify partition ----
    if (tid == 0) {
        // hwreg imm = (size-1=3)<<11 | (offset=0)<<6 | (id=20, HW_REG_XCC_ID)
        const int x = (int)(__builtin_amdgcn_s_getreg(6164) & 7u);
        __hip_atomic_store(&xcds[wgid], x + 1, __ATOMIC_RELEASE,
                           __HIP_MEMORY_SCOPE_AGENT);
    }
    {
        int v;
        do {
            v = __hip_atomic_load(&xcds[tid], __ATOMIC_RELAXED,
                                  __HIP_MEMORY_SCOPE_AGENT);
        } while (v == 0);
        sx[tid] = v - 1;
    }
    __syncthreads();
    if (tid == 0) {
        int cnt[8] = {};
        for (int w = 0; w < 256; ++w) cnt[sx[w] & 7]++;
        bool uni = true;
        for (int i = 0; i < 8; ++i) uni = uni && (cnt[i] == 32);
        int rank = 0;
        const int mine = sx[wgid];
        for (int w = 0; w < wgid; ++w) rank += (sx[w] == mine);
        int g, slot;
        if (uni) { g = mine & 7;  slot = rank; }
        else     { g = wgid & 7;  slot = wgid >> 3; }
        s_info = (uni ? 0x10000 : 0) | (g << 8) | slot;
    }
    __syncthreads();
    const int fast = (s_info >> 16) & 1;
    const int g    = (s_info >> 8) & 7;
    const int sub  = s_info & 0xff;
    const int j0   = sub * 32;
    const int b0   = g * BPG;

    // compute roles (note: kc*16 + jp == tid)
    const int kc = wave * 4 + (lane >> 4);   // 0..15 (k-chunk of 64)
    const int jp = lane & 15;                // 0..15 (j-pair)
    // output roles
    const int o_jl = tid & 31, o_bl = tid >> 5;
    const int oj = j0 + o_jl;

    // Preload Ww[j0+jp*2 .. +1][kc*64 .. +63] into registers (128 VGPR).
    float wreg[2][64];
    {
        const float* base = Ww + (size_t)(j0 + jp * 2) * RH + kc * 64;
        #pragma unroll
        for (int jj = 0; jj < 2; ++jj)
            #pragma unroll
            for (int ki = 0; ki < 64; ki += 4) {
                float4 v = *(const float4*)(base + (size_t)jj * RH + ki);
                wreg[jj][ki + 0] = v.x; wreg[jj][ki + 1] = v.y;
                wreg[jj][ki + 2] = v.z; wreg[jj][ki + 3] = v.w;
            }
    }
    const float wb = Wb[oj];

    int* gflags = flags + g * WPG;

    for (int t = 0; t < RS; ++t) {
        // Vx prefetch: issued before the poll; its HBM latency hides under
        // the flag wait ("memory" clobber in the poll pins issue order).
        float* cell = hseq + (size_t)t * (RB * RH) + (size_t)(b0 + o_bl) * RH + oj;
        const float vx = *cell;

        float red = 0.f;
        if (t > 0) {
            // 1) wait until all 32 producers published h_{t-1}.
            if (wave == 0) {
                const int* fp = gflags + (lane & 31);
                if (fast) {
                    int f;
                    do {
                        asm volatile("global_load_dword %0, %1, off sc0\n\t"
                                     "s_waitcnt vmcnt(0)"
                                     : "=v"(f) : "v"(fp) : "memory");
                    } while (f < t);
                } else {
                    while (__hip_atomic_load(fp, __ATOMIC_RELAXED,
                                             __HIP_MEMORY_SCOPE_AGENT) < t) {}
                }
            }
            __syncthreads();

            // 2) stage h_{t-1} into LDS.
            const float* srcf = hex + ((size_t)((t - 1) & 1) * NG + g) * (RH * BPG);
            if (fast) {
                const f32x4* src = (const f32x4*)srcf;
                f32x4 r0, r1, r2, r3, r4, r5, r6, r7;
#define LDX(i, r) asm volatile("global_load_dwordx4 %0, %1, off sc0" \
                               : "=v"(r) : "v"(src + (tid + 256 * i)))
                LDX(0, r0); LDX(1, r1); LDX(2, r2); LDX(3, r3);
                LDX(4, r4); LDX(5, r5); LDX(6, r6); LDX(7, r7);
#undef LDX
                // "+v" ties make this asm the last def of r0..r7, so the LDS
                // stores below cannot be scheduled before the drain.
                asm volatile("s_waitcnt vmcnt(0)"
                             : "+v"(r0), "+v"(r1), "+v"(r2), "+v"(r3),
                               "+v"(r4), "+v"(r5), "+v"(r6), "+v"(r7));
#define STX(i, r) { const int idx4 = tid + 256 * i; const int k = idx4 >> 1; \
                    *(f32x4*)&Hs[k * 8 + (k >> 6) * 4 + (idx4 & 1) * 4] = r; }
                STX(0, r0); STX(1, r1); STX(2, r2); STX(3, r3);
                STX(4, r4); STX(5, r5); STX(6, r6); STX(7, r7);
#undef STX
            } else {
                const unsigned long long* src = (const unsigned long long*)srcf;
                #pragma unroll
                for (int i = 0; i < 16; ++i) {
                    const int idx = tid + 256 * i;     // float2 index
                    unsigned long long u = __hip_atomic_load(src + idx,
                        __ATOMIC_RELAXED, __HIP_MEMORY_SCOPE_AGENT);
                    union { unsigned long long u; float f[2]; } cv; cv.u = u;
                    const int k = idx >> 2, q = idx & 3;
                    const int base = k * 8 + (k >> 6) * 4 + q * 2;
                    Hs[base] = cv.f[0]; Hs[base + 1] = cv.f[1];
                }
            }
            __syncthreads();

            // 3) 64x16 FMA loop over this thread's k-chunk.
            float acc[16];
            #pragma unroll
            for (int i = 0; i < 16; ++i) acc[i] = 0.f;

            const f32x4* hv = (const f32x4*)Hs;
            const int hbase = kc * 129;                // (kc*516)/4
            #pragma unroll
            for (int ki = 0; ki < 64; ++ki) {
                const f32x4 h0 = hv[hbase + ki * 2];
                const f32x4 h1 = hv[hbase + ki * 2 + 1];
                const float w0 = wreg[0][ki], w1 = wreg[1][ki];
                acc[0]  = fmaf(w0, h0.x, acc[0]);  acc[1]  = fmaf(w0, h0.y, acc[1]);
                acc[2]  = fmaf(w0, h0.z, acc[2]);  acc[3]  = fmaf(w0, h0.w, acc[3]);
                acc[4]  = fmaf(w0, h1.x, acc[4]);  acc[5]  = fmaf(w0, h1.y, acc[5]);
                acc[6]  = fmaf(w0, h1.z, acc[6]);  acc[7]  = fmaf(w0, h1.w, acc[7]);
                acc[8]  = fmaf(w1, h0.x, acc[8]);  acc[9]  = fmaf(w1, h0.y, acc[9]);
                acc[10] = fmaf(w1, h0.z, acc[10]); acc[11] = fmaf(w1, h0.w, acc[11]);
                acc[12] = fmaf(w1, h1.x, acc[12]); acc[13] = fmaf(w1, h1.y, acc[13]);
                acc[14] = fmaf(w1, h1.z, acc[14]); acc[15] = fmaf(w1, h1.w, acc[15]);
            }

            // 4) k-split partials -> LDS. v-major stride-272: writes are
            //    lane-stride-1 (conflict-free), reads 2-way (free). Replaces
            //    the 8-way-conflict b128 transpose (1.67e8 bank conflicts).
            float* rp = Red + tid;   // tid == kc*16 + jp
            #pragma unroll
            for (int v = 0; v < 16; ++v) rp[v * 272] = acc[v];
            __syncthreads();

            // 5) 16-way k reduce (kc-ascending order -> bit-identical).
            const int vb = ((o_jl & 1) * 8 + o_bl) * 272 + (o_jl >> 1);
            #pragma unroll
            for (int kk = 0; kk < 16; ++kk) red += Red[vb + kk * 16];
        }

        const float h = tanhf(red + wb + vx);

        if (t < RS - 1) {
            float* dst = hex + ((size_t)(t & 1) * NG + g) * (RH * BPG)
                             + (size_t)oj * BPG + o_bl;
            if (fast) {
                *(volatile float*)dst = h;   // write-through L1 -> same-XCD L2
            } else {
                __hip_atomic_store(dst, h, __ATOMIC_RELAXED,
                                   __HIP_MEMORY_SCOPE_AGENT);
            }
            __syncthreads();   // drains vmcnt(0) for every wave (publish done)
            if (tid == 0) {
                if (fast) ((volatile int*)gflags)[sub] = t + 1;
                else __hip_atomic_store(&gflags[sub], t + 1, __ATOMIC_RELEASE,
                                        __HIP_MEMORY_SCOPE_AGENT);
            }
            // hseq HBM store AFTER the flag: its ack drains during the next
            // step's wait instead of delaying the group.
            *cell = h;
        } else {
            *cell = h;
            hfin[(size_t)(b0 + o_bl) * RH + oj] = h;
        }
    }
}

// ---------------------------------------------------------------------------
extern "C" void kernel_launch(void* const* d_in, const int* in_sizes, int n_in,
                              void* d_out, int out_size, void* d_ws, size_t ws_size,
                              hipStream_t stream) {
    const float* x  = (const float*)d_in[0];  // (S,B,I)
    const float* Ww = (const float*)d_in[1];  // (H,H)
    const float* Wb = (const float*)d_in[2];  // (H)
    const float* Vw = (const float*)d_in[3];  // (H,I)
    const float* Vb = (const float*)d_in[4];  // (H)

    float* out  = (float*)d_out;
    float* hseq = out;                                  // (S,B,H)
    float* hfin = out + (size_t)RS * RB * RH;           // (B,H)

    // Workspace (zeroed by harness reset before every launch):
    // [0,1024)    : 256 int flags (8 groups x 32)
    // [1024,2048) : 256 int census entries (xcd id + 1 per WG)
    // [2048, +512KB): 2 x 8 groups x 1024 x 8 float h-exchange
    int*   flags = (int*)d_ws;
    int*   xcds  = (int*)((char*)d_ws + 1024);
    float* hex   = (float*)((char*)d_ws + 2048);

    // 1) Vx = x @ Vw^T + Vb  -> hseq (consumed in place by recurrence)
    {
        dim3 grid(RH / 64, (RS * RB) / 64);
        dim3 block(16, 16);
        vx_gemm<<<grid, block, 0, stream>>>(x, Vw, Vb, hseq, RS * RB, RH, RI);
    }

    // 2) Persistent recurrence: census-grouped, L2-local fast path.
    rnn_persistent<<<dim3(NG * WPG), dim3(256), 0, stream>>>(Ww, Wb, hseq, hfin,
                                                             hex, flags, xcds);
}